// Round 2
// baseline (47.515 us; speedup 1.0000x reference)
//
#include <hip/hip_runtime.h>
#include <math.h>

#define DIM  512
#define NS   4096
#define NW   16384   // M * N_GRID = 128*128

// ws layout (in floats):
//   [0      .. 511  ]  S[d]    = sum_s x[d,s]
//   [512    .. 1023 ]  xcur[d] = x[d, NS-1]
//   [1024   .. 17407]  key[w]  = 4096*w_norm[w] - 2*dot(S, w_row)
//   ints at float-offset 17408: [bmu, new_output, update]

// ---------------- Kernel 1: row sums of x + last column ----------------
__global__ __launch_bounds__(256)
void k_rowsum(const float* __restrict__ x, float* __restrict__ S,
              float* __restrict__ xcur) {
    int d = blockIdx.x;                       // 0..511
    const float* row = x + (size_t)d * NS;    // contiguous 4096 floats
    float s = 0.f;
    for (int i = threadIdx.x; i < NS; i += 256) s += row[i];
    // wave reduce (64-lane) then cross-wave via LDS
    for (int off = 32; off; off >>= 1) s += __shfl_down(s, off, 64);
    __shared__ float sm[4];
    int lane = threadIdx.x & 63, wv = threadIdx.x >> 6;
    if (lane == 0) sm[wv] = s;
    __syncthreads();
    if (threadIdx.x == 0) {
        S[d]    = sm[0] + sm[1] + sm[2] + sm[3];
        xcur[d] = row[NS - 1];
    }
}

// ---------------- Kernel 2: per-row key = 4096*||w||^2 - 2*<S,w> -------
__global__ __launch_bounds__(256)
void k_keys(const float* __restrict__ weights, const float* __restrict__ S,
            float* __restrict__ key) {
    int wv   = threadIdx.x >> 6;              // wave in block: 0..3
    int lane = threadIdx.x & 63;
    int w    = blockIdx.x * 4 + wv;           // weight row
    const float4* wr = (const float4*)(weights + (size_t)w * DIM);
    const float4* S4 = (const float4*)S;
    float wn = 0.f, dt = 0.f;
#pragma unroll
    for (int it = 0; it < 2; ++it) {
        int i = lane + 64 * it;               // float4 index 0..127
        float4 v  = wr[i];
        float4 sv = S4[i];
        wn += v.x * v.x + v.y * v.y + v.z * v.z + v.w * v.w;
        dt += v.x * sv.x + v.y * sv.y + v.z * sv.z + v.w * sv.w;
    }
    for (int off = 32; off; off >>= 1) {
        wn += __shfl_down(wn, off, 64);
        dt += __shfl_down(dt, off, 64);
    }
    if (lane == 0)
        key[w] = (float)(4096.0 * (double)wn - 2.0 * (double)dt);
}

// ---------------- Kernel 3: argmin + scalar trend logic ----------------
__global__ __launch_bounds__(256)
void k_argmin(const float* __restrict__ key,
              const int* __restrict__ output_layer,
              const int* __restrict__ lstm_p, const int* __restrict__ real_p,
              float* __restrict__ out, int* __restrict__ wsi) {
    float best = INFINITY;
    int   bidx = NW;
    for (int i = threadIdx.x; i < NW; i += 256) {
        float k = key[i];
        if (k < best) { best = k; bidx = i; }   // ascending scan => first index kept
    }
    __shared__ float bk[256];
    __shared__ int   bi[256];
    bk[threadIdx.x] = best;
    bi[threadIdx.x] = bidx;
    __syncthreads();
    for (int s = 128; s; s >>= 1) {
        if (threadIdx.x < s) {
            float ok = bk[threadIdx.x + s];
            int   oi = bi[threadIdx.x + s];
            if (ok < bk[threadIdx.x] ||
                (ok == bk[threadIdx.x] && oi < bi[threadIdx.x])) {
                bk[threadIdx.x] = ok;
                bi[threadIdx.x] = oi;
            }
        }
        __syncthreads();
    }
    if (threadIdx.x == 0) {
        int bmu  = bi[0];
        int som  = output_layer[bmu];
        int lstm = lstm_p[0], real = real_p[0];
        int lstm_err = real - lstm; if (lstm_err < 0) lstm_err = -lstm_err;
        int som_err  = real - som;  if (som_err  < 0) som_err  = -som_err;
        int mx = lstm_err > som_err ? lstm_err : som_err;
        bool c1 = (mx == 0);
        bool c2 = (mx > 0) && (lstm_err == 0);
        bool c3 = (mx > 0) && (som_err == 0);
        int penalty = c1 ? -1 : (c2 ? 1 : 0);
        int new_out = (c1 || c2) ? lstm : (c3 ? som : real);
        int update  = (c1 || (c3 && !c2)) ? 1 : 0;
        out[0] = (float)penalty;
        out[1] = (float)new_out;
        wsi[0] = bmu;
        wsi[1] = new_out;
        wsi[2] = update;
    }
}

// ---------------- Kernel 4: out_layer_new (as float) -------------------
__global__ __launch_bounds__(256)
void k_outlayer(const int* __restrict__ output_layer,
                const int* __restrict__ wsi, float* __restrict__ out_ol) {
    int i = blockIdx.x * 256 + threadIdx.x;
    if (i < NW) {
        int v = (i == wsi[0]) ? wsi[1] : output_layer[i];
        out_ol[i] = (float)v;
    }
}

// ---------------- Kernel 5: weights_new ---------------------------------
__global__ __launch_bounds__(256)
void k_weights(const float* __restrict__ weights,
               const int* __restrict__ locations,
               const float* __restrict__ xcur,
               const int* __restrict__ wsi,
               float* __restrict__ out_w) {
    int wv   = threadIdx.x >> 6;
    int lane = threadIdx.x & 63;
    int w    = blockIdx.x * 4 + wv;           // weight row
    int bmu  = wsi[0];
    int upd  = wsi[2];
    float lr = 0.f;
    if (upd) {
        float dx = (float)(locations[2 * w]     - locations[2 * bmu]);
        float dy = (float)(locations[2 * w + 1] - locations[2 * bmu + 1]);
        double d2 = (double)(dx * dx + dy * dy);
        lr = (float)(0.15 * exp(-d2 / 92.16));   // sigma_op^2 = (64*0.15)^2
    }
    const float4* wr = (const float4*)(weights + (size_t)w * DIM);
    const float4* xc = (const float4*)xcur;
    float4* ow = (float4*)(out_w + (size_t)w * DIM);
#pragma unroll
    for (int it = 0; it < 2; ++it) {
        int i = lane + 64 * it;
        float4 v = wr[i];
        float4 c = xc[i];
        float4 r;
        r.x = v.x + lr * (c.x - v.x);
        r.y = v.y + lr * (c.y - v.y);
        r.z = v.z + lr * (c.z - v.z);
        r.w = v.w + lr * (c.w - v.w);
        ow[i] = r;
    }
}

extern "C" void kernel_launch(void* const* d_in, const int* in_sizes, int n_in,
                              void* d_out, int out_size, void* d_ws, size_t ws_size,
                              hipStream_t stream) {
    const float* x            = (const float*)d_in[0];   // (512, 4096)
    const float* weights      = (const float*)d_in[1];   // (16384, 512)
    const int*   locations    = (const int*)  d_in[2];   // (16384, 2)
    const int*   output_layer = (const int*)  d_in[3];   // (16384,)
    const int*   lstm_trend   = (const int*)  d_in[4];   // scalar
    const int*   real_trend   = (const int*)  d_in[5];   // scalar

    float* ws   = (float*)d_ws;
    float* S    = ws;             // 512
    float* xcur = ws + 512;       // 512
    float* key  = ws + 1024;      // 16384
    int*   wsi  = (int*)(ws + 1024 + NW);  // [bmu, new_output, update]

    float* out      = (float*)d_out;
    float* out_w    = out + 2;                       // 16384*512
    float* out_ol   = out + 2 + (size_t)NW * DIM;    // 16384

    k_rowsum <<<DIM,     256, 0, stream>>>(x, S, xcur);
    k_keys   <<<NW / 4,  256, 0, stream>>>(weights, S, key);
    k_argmin <<<1,       256, 0, stream>>>(key, output_layer, lstm_trend,
                                           real_trend, out, wsi);
    k_outlayer<<<NW/256, 256, 0, stream>>>(output_layer, wsi, out_ol);
    k_weights<<<NW / 4,  256, 0, stream>>>(weights, locations, xcur, wsi, out_w);
}

// Round 3
// 31.726 us; speedup vs baseline: 1.4977x; 1.4977x over previous
//
#include <hip/hip_runtime.h>
#include <math.h>

#define DIM  512
#define NS   4096
#define NW   16384     // 128*128
#define GW   128       // grid width
#define BOX  31        // fixup radius: skipped rows have d2 >= 1024, lr < 2.3e-6
#define NB2  2048      // blocks in k_keys (8 rows each)

// ws float layout:
//   [0    .. 511 ]  S[d] = sum_s x[d,s]
//   [512  .. 1023]  xcur[d] = x[d, NS-1]
//   [1024 .. 5119]  blockmin: 2048 x u64 packed (ukey<<32 | row)
//   ints at float offset 5120: [bmu, new_output, update, bmu_i, bmu_j]

// ---------------- K1: row sums of x + last column ----------------------
__global__ __launch_bounds__(256)
void k_rowsum(const float* __restrict__ x, float* __restrict__ S,
              float* __restrict__ xcur) {
    int d = blockIdx.x;                         // 0..511
    const float4* row = (const float4*)(x + (size_t)d * NS);   // 1024 float4
    float s = 0.f;
    for (int i = threadIdx.x; i < NS / 4; i += 256) {
        float4 v = row[i];
        s += v.x + v.y + v.z + v.w;
    }
    for (int off = 32; off; off >>= 1) s += __shfl_down(s, off, 64);
    __shared__ float sm[4];
    if ((threadIdx.x & 63) == 0) sm[threadIdx.x >> 6] = s;
    __syncthreads();
    if (threadIdx.x == 0) {
        S[d]    = sm[0] + sm[1] + sm[2] + sm[3];
        xcur[d] = x[(size_t)d * NS + NS - 1];
    }
}

// ------- K2: key per row + copy weights->out_w + per-block argmin ------
__global__ __launch_bounds__(256)
void k_keys(const float* __restrict__ weights, const float* __restrict__ S,
            float* __restrict__ out_w,
            unsigned long long* __restrict__ blockmin) {
    int wv = threadIdx.x >> 6, lane = threadIdx.x & 63;
    const float4* S4 = (const float4*)S;
    float4 s0 = S4[lane], s1 = S4[lane + 64];
    unsigned long long best = ~0ULL;
#pragma unroll
    for (int rr = 0; rr < 2; ++rr) {
        int w = blockIdx.x * 8 + wv * 2 + rr;
        const float4* wr = (const float4*)(weights + (size_t)w * DIM);
        float4*       ow = (float4*)(out_w + (size_t)w * DIM);
        float4 v0 = wr[lane], v1 = wr[lane + 64];
        ow[lane]      = v0;                     // copy pass (most rows final)
        ow[lane + 64] = v1;
        float wn = v0.x*v0.x + v0.y*v0.y + v0.z*v0.z + v0.w*v0.w
                 + v1.x*v1.x + v1.y*v1.y + v1.z*v1.z + v1.w*v1.w;
        float dt = v0.x*s0.x + v0.y*s0.y + v0.z*s0.z + v0.w*s0.w
                 + v1.x*s1.x + v1.y*s1.y + v1.z*s1.z + v1.w*s1.w;
        for (int off = 32; off; off >>= 1) {
            wn += __shfl_down(wn, off, 64);
            dt += __shfl_down(dt, off, 64);
        }
        if (lane == 0) {
            double kd = 4096.0 * (double)wn - 2.0 * (double)dt;
            float  kf = (float)kd;
            unsigned u = __float_as_uint(kf);
            u = (u & 0x80000000u) ? ~u : (u | 0x80000000u);   // monotone map
            unsigned long long pk = ((unsigned long long)u << 32) | (unsigned)w;
            if (pk < best) best = pk;
        }
    }
    __shared__ unsigned long long sm[4];
    if (lane == 0) sm[wv] = best;
    __syncthreads();
    if (threadIdx.x == 0) {
        unsigned long long b = sm[0];
#pragma unroll
        for (int i = 1; i < 4; ++i) if (sm[i] < b) b = sm[i];
        blockmin[blockIdx.x] = b;
    }
}

// ---------------- K3: global argmin + scalar trend logic ---------------
__global__ __launch_bounds__(256)
void k_argmin(const unsigned long long* __restrict__ blockmin,
              const int* __restrict__ output_layer,
              const int* __restrict__ locations,
              const int* __restrict__ lstm_p, const int* __restrict__ real_p,
              float* __restrict__ out, int* __restrict__ wsi) {
    unsigned long long best = ~0ULL;
    for (int i = threadIdx.x; i < NB2; i += 256) {
        unsigned long long v = blockmin[i];
        if (v < best) best = v;
    }
    for (int off = 32; off; off >>= 1) {
        unsigned long long o = __shfl_down(best, off, 64);
        if (o < best) best = o;
    }
    __shared__ unsigned long long sm[4];
    if ((threadIdx.x & 63) == 0) sm[threadIdx.x >> 6] = best;
    __syncthreads();
    if (threadIdx.x == 0) {
        unsigned long long b = sm[0];
#pragma unroll
        for (int i = 1; i < 4; ++i) if (sm[i] < b) b = sm[i];
        int bmu  = (int)(b & 0xFFFFFFFFu);
        int som  = output_layer[bmu];
        int lstm = lstm_p[0], real = real_p[0];
        int lstm_err = real - lstm; if (lstm_err < 0) lstm_err = -lstm_err;
        int som_err  = real - som;  if (som_err  < 0) som_err  = -som_err;
        int mx = lstm_err > som_err ? lstm_err : som_err;
        bool c1 = (mx == 0);
        bool c2 = (mx > 0) && (lstm_err == 0);
        bool c3 = (mx > 0) && (som_err == 0);
        int penalty = c1 ? -1 : (c2 ? 1 : 0);
        int new_out = (c1 || c2) ? lstm : (c3 ? som : real);
        int update  = (c1 || (c3 && !c2)) ? 1 : 0;
        out[0] = (float)penalty;
        out[1] = (float)new_out;
        wsi[0] = bmu;
        wsi[1] = new_out;
        wsi[2] = update;
        wsi[3] = locations[2 * bmu];
        wsi[4] = locations[2 * bmu + 1];
    }
}

// ------- K4: out_layer_new + weight fixup in 63x63 box around BMU ------
// blocks 0..62: fixup row i = bmu_i + (blk-31); blocks 63..78: out_ol.
__global__ __launch_bounds__(256)
void k_finalize(const float* __restrict__ weights,
                const float* __restrict__ xcur,
                const int* __restrict__ output_layer,
                const int* __restrict__ wsi,
                float* __restrict__ out_w, float* __restrict__ out_ol) {
    int bmu = wsi[0], new_out = wsi[1], update = wsi[2];
    if (blockIdx.x >= 63) {
        int base = (int)(blockIdx.x - 63) * 1024 + threadIdx.x;
#pragma unroll
        for (int k = 0; k < 4; ++k) {
            int idx = base + k * 256;
            int v = (idx == bmu) ? new_out : output_layer[idx];
            out_ol[idx] = (float)v;
        }
        return;
    }
    if (!update) return;                         // out_w already == weights
    int bi = wsi[3], bj = wsi[4];
    int di = (int)blockIdx.x - BOX;
    int i  = bi + di;
    if (i < 0 || i >= GW) return;
    int wv = threadIdx.x >> 6, lane = threadIdx.x & 63;
    const float4* xc4 = (const float4*)xcur;
    float4 c0 = xc4[lane], c1 = xc4[lane + 64];
    for (int t = wv; t < 2 * BOX + 1; t += 4) {
        int dj = t - BOX;
        int j  = bj + dj;
        if (j < 0 || j >= GW) continue;
        int r = i * GW + j;
        float d2 = (float)(di * di + dj * dj);
        float lr = 0.15f * expf(-d2 / 92.16f);
        const float4* wr = (const float4*)(weights + (size_t)r * DIM);
        float4*       ow = (float4*)(out_w + (size_t)r * DIM);
        float4 v0 = wr[lane], v1 = wr[lane + 64];
        float4 o0, o1;
        o0.x = v0.x + lr * (c0.x - v0.x);  o0.y = v0.y + lr * (c0.y - v0.y);
        o0.z = v0.z + lr * (c0.z - v0.z);  o0.w = v0.w + lr * (c0.w - v0.w);
        o1.x = v1.x + lr * (c1.x - v1.x);  o1.y = v1.y + lr * (c1.y - v1.y);
        o1.z = v1.z + lr * (c1.z - v1.z);  o1.w = v1.w + lr * (c1.w - v1.w);
        ow[lane]      = o0;
        ow[lane + 64] = o1;
    }
}

extern "C" void kernel_launch(void* const* d_in, const int* in_sizes, int n_in,
                              void* d_out, int out_size, void* d_ws, size_t ws_size,
                              hipStream_t stream) {
    const float* x            = (const float*)d_in[0];   // (512, 4096)
    const float* weights      = (const float*)d_in[1];   // (16384, 512)
    const int*   locations    = (const int*)  d_in[2];   // (16384, 2)
    const int*   output_layer = (const int*)  d_in[3];   // (16384,)
    const int*   lstm_trend   = (const int*)  d_in[4];   // scalar
    const int*   real_trend   = (const int*)  d_in[5];   // scalar

    float* ws   = (float*)d_ws;
    float* S    = ws;                                     // 512
    float* xcur = ws + 512;                               // 512
    unsigned long long* blockmin = (unsigned long long*)(ws + 1024);  // 2048 u64
    int*   wsi  = (int*)(ws + 1024 + 2 * NB2);            // 5 ints

    float* out    = (float*)d_out;
    float* out_w  = out + 2;                              // 16384*512
    float* out_ol = out + 2 + (size_t)NW * DIM;           // 16384

    k_rowsum  <<<DIM,  256, 0, stream>>>(x, S, xcur);
    k_keys    <<<NB2,  256, 0, stream>>>(weights, S, out_w, blockmin);
    k_argmin  <<<1,    256, 0, stream>>>(blockmin, output_layer, locations,
                                         lstm_trend, real_trend, out, wsi);
    k_finalize<<<79,   256, 0, stream>>>(weights, xcur, output_layer, wsi,
                                         out_w, out_ol);
}